// Round 11
// baseline (1310.757 us; speedup 1.0000x reference)
//
#include <hip/hip_runtime.h>
#include <hip/hip_bf16.h>
#include <stdint.h>

#define HH 101
#define WW 31
#define NN 3131
#define NPAD 3136
#define BB 32
#define NH 8
#define CDIM 256
#define GG 64
#define HP 103
#define WP 33

typedef __attribute__((ext_vector_type(8))) short bf16x8;
typedef __attribute__((ext_vector_type(4))) float f32x4;
typedef __attribute__((ext_vector_type(4))) unsigned short ushort4_t;
typedef __attribute__((ext_vector_type(8))) unsigned short ushort8_t;
typedef __attribute__((ext_vector_type(4))) float float4_t;

static __device__ __forceinline__ unsigned short f2bf(float f) {
  union { float f; uint32_t u; } v; v.f = f;
  uint32_t u = v.u;
  return (unsigned short)((u + 0x7fffu + ((u >> 16) & 1u)) >> 16);
}
static __device__ __forceinline__ float bf2f(unsigned short h) {
  union { uint32_t u; float f; } v; v.u = ((uint32_t)h) << 16;
  return v.f;
}
static __device__ __forceinline__ void gload_lds16(const void* g, void* l) {
  __builtin_amdgcn_global_load_lds((const __attribute__((address_space(1))) void*)g,
                                   (__attribute__((address_space(3))) void*)l, 16, 0, 0);
}
// m204 bijective XCD swizzle
static __device__ __forceinline__ int xcd_swz(int bid, int nwg) {
  int q = nwg >> 3, r = nwg & 7;
  int xcd = bid & 7, pos = bid >> 3;
  int base = (xcd < r) ? xcd * (q + 1) : r * (q + 1) + (xcd - r) * q;
  return base + pos;
}

// ---------------- K0: pad + cast x -> bf16 (CB, HP, WP, C) ----------------
__global__ void k_pad(const float* __restrict__ x, unsigned short* __restrict__ xpad, int b0) {
  const int xx = blockIdx.x, yy = blockIdx.y, b = blockIdx.z;
  const int t = threadIdx.x;
  ushort4_t o; o.x = 0; o.y = 0; o.z = 0; o.w = 0;
  if (yy >= 1 && yy <= HH && xx >= 1 && xx <= WW) {
    const int n = (yy - 1) * WW + (xx - 1);
    const float4_t v = *(const float4_t*)(x + (((int64_t)(b0 + b) * NN + n) * CDIM + t * 4));
    o.x = f2bf(v.x); o.y = f2bf(v.y); o.z = f2bf(v.z); o.w = f2bf(v.w);
  }
  *(ushort4_t*)(xpad + (((int64_t)b * HP + yy) * WP + xx) * CDIM + t * 4) = o;
}

// ---------------- K1: pack conv weights, bias, gate_w ----------------
__global__ void k_wpack(const float* __restrict__ fxw, const float* __restrict__ xw,
                        const float* __restrict__ fxb, const float* __restrict__ xb,
                        const float* __restrict__ gw,
                        unsigned short* __restrict__ Wb, float* __restrict__ bias,
                        unsigned short* __restrict__ gwb) {
  int tid = blockIdx.x * blockDim.x + threadIdx.x;
  const int total = 9 * 1024 * 256;
  if (tid < total) {
    int cin = tid & 255; int rest = tid >> 8; int co = rest & 1023; int t = rest >> 10;
    float v = (co < 512) ? fxw[(int64_t)co * 2304 + cin * 9 + t]
                         : xw[(int64_t)(co - 512) * 2304 + cin * 9 + t];
    Wb[tid] = f2bf(v);
  }
  if (tid < 1024) bias[tid] = (tid < 512) ? fxb[tid] : xb[tid - 512];
  if (tid < 4096) gwb[tid] = f2bf(gw[tid]);
}

// ---------------- K1b: Pt[h][co][i] = sum_c mlp_w[i][c] * out_w[co][h*64+c] (bf16) --------
__global__ void k_pprep(const float* __restrict__ mlp, const float* __restrict__ outw,
                        unsigned short* __restrict__ Pt) {
  int h = blockIdx.x >> 6, i = blockIdx.x & 63, co = threadIdx.x;
  float a = 0.f;
  for (int c = 0; c < 64; ++c) a += mlp[i * 64 + c] * outw[(int64_t)co * 512 + h * 64 + c];
  Pt[((int64_t)h * 256 + co) * 64 + i] = f2bf(a);
}

// ---------------- K1c: zero pad tail cols of fxT ----------
__global__ void k_padzero(unsigned short* __restrict__ fxT, int CB) {
  int tid = blockIdx.x * blockDim.x + threadIdx.x;
  if (tid >= CB * 2560) return;
  int j = tid % 5; int rc = tid / 5;   // rc < CB*512 = (b*8+h)*64+c
  fxT[(int64_t)rc * NPAD + NN + j] = 0;
}

// ---------------- K2: 256x256 conv (R7 K-loop) + fused eig epilogue (coalesced) ---------
// 8 waves 4M x 2N (wave 64x128), BK=64, 2 LDS buffers (128KB), reg-pipelined counted
// waits (vmcnt(4), lgkm(4/8), never 0 mid-loop). bx<2 -> fxT. bx>=2 -> fused gate:
// stage xmid->LDS (wave-local), logits MFMA, softmax -> egt[g][n] LDS, then
// COALESCED eigT (128B runs per g-row) and eigN (128B per n-row) global stores.
__launch_bounds__(512, 2)
__global__ void k_conv8(const unsigned short* __restrict__ xpad,
                        const unsigned short* __restrict__ Wb,
                        const float* __restrict__ bias,
                        const unsigned short* __restrict__ gwb,
                        const float* __restrict__ gateb,
                        const float* __restrict__ temperature,
                        const float* __restrict__ inver,
                        unsigned short* __restrict__ fxT,
                        unsigned short* __restrict__ eigT,
                        unsigned short* __restrict__ eigN) {
  extern __shared__ unsigned short lds[];   // 2 x 32768 elems (K-loop); reused by epilogue
  const int swz = xcd_swz(blockIdx.x, gridDim.x);
  const int r   = swz % 52;
  const int b   = swz / 52;
  const int bx  = r & 3;
  const int mt  = r >> 2;
  const int tid = threadIdx.x, wid = tid >> 6, lane = tid & 63;
  const int wm = wid & 3, wn = wid >> 2;           // 4 M-waves x 2 N-waves
  const int arow = lane & 15, col16 = lane >> 4;
  const int n00 = mt * 256, co00 = bx * 256;

  const int srow = wid * 16 + (lane >> 2);
  const int tc   = ((lane & 3) ^ ((lane >> 3) & 3)) * 8;
  int na0 = n00 + srow;        if (na0 >= NN) na0 = NN - 1;
  int na1 = n00 + srow + 128;  if (na1 >= NN) na1 = NN - 1;
  const int y0 = na0 / WW, x0v = na0 % WW;
  const int y1 = na1 / WW, x1v = na1 % WW;
  const unsigned short* aS0 = xpad + ((int64_t)(b * HP + y0) * WP + x0v) * CDIM + tc;
  const unsigned short* aS1 = xpad + ((int64_t)(b * HP + y1) * WP + x1v) * CDIM + tc;
  const unsigned short* bS0 = Wb + (int64_t)(co00 + srow) * CDIM + tc;
  const unsigned short* bS1 = Wb + (int64_t)(co00 + srow + 128) * CDIM + tc;

  const int rdsz = (col16 ^ ((arow >> 1) & 3)) * 8;

  f32x4 acc[4][8] = {};
  bf16x8 a0[4], a1[4], b03[4], b47[4];

#define STAGE_A(s, kk, aoffv)                                        \
  { unsigned short* d = lds + (s) * 32768 + (kk) * 8192 + wid * 512; \
    gload_lds16(aS0 + (aoffv) + (kk) * 32, d);                       \
    gload_lds16(aS1 + (aoffv) + (kk) * 32, d + 4096); }
#define STAGE_B(s, kk, boffv)                                                \
  { unsigned short* d = lds + (s) * 32768 + 16384 + (kk) * 8192 + wid * 512; \
    gload_lds16(bS0 + (boffv) + (kk) * 32, d);                               \
    gload_lds16(bS1 + (boffv) + (kk) * 32, d + 4096); }
#define KOFF(ks, aoffv, boffv)                              \
  { const int tap = (ks) >> 2;                              \
    const int dy = (tap >= 6) + (tap >= 3);                 \
    const int dx = tap - dy * 3;                            \
    const int cb = ((ks) & 3) << 6;                         \
    aoffv = (dy * WP + dx) * CDIM + cb;                     \
    boffv = tap * 262144 + cb; }
#define RD_A(dst, s, kk, mf)                                                             \
  dst = *(const bf16x8*)(lds + (s) * 32768 + (kk) * 8192 +                               \
                         (wm * 64 + (mf) * 16 + arow) * 32 + rdsz);
#define RD_B(dst, s, kk, nf)                                                             \
  dst = *(const bf16x8*)(lds + (s) * 32768 + 16384 + (kk) * 8192 +                       \
                         (wn * 128 + (nf) * 16 + arow) * 32 + rdsz);
#define MFMA16(aset, bset, nbase)                                                        \
  __builtin_amdgcn_s_setprio(1);                                                         \
  _Pragma("unroll")                                                                      \
  for (int mf = 0; mf < 4; ++mf) {                                                       \
    _Pragma("unroll")                                                                    \
    for (int nf = 0; nf < 4; ++nf)                                                       \
      acc[mf][(nbase) + nf] =                                                            \
        __builtin_amdgcn_mfma_f32_16x16x32_bf16(aset[mf], bset[nf], acc[mf][(nbase) + nf], 0, 0, 0); \
  }                                                                                      \
  __builtin_amdgcn_s_setprio(0);

  // ---- prologue ----
  int aoff0, boff0;
  KOFF(0, aoff0, boff0);
  STAGE_A(0, 0, aoff0); STAGE_B(0, 0, boff0);
  STAGE_A(0, 1, aoff0); STAGE_B(0, 1, boff0);
  asm volatile("s_waitcnt vmcnt(4)" ::: "memory");
  __builtin_amdgcn_s_barrier();
  asm volatile("" ::: "memory");
  #pragma unroll
  for (int i = 0; i < 4; ++i) { RD_A(a0[i], 0, 0, i); }
  #pragma unroll
  for (int i = 0; i < 4; ++i) { RD_B(b03[i], 0, 0, i); }

  #pragma unroll 1
  for (int t = 0; t < 36; ++t) {
    const int cur = t & 1, nxt = cur ^ 1;
    const int tn = (t < 35) ? t + 1 : 35;
    int aoffn, boffn;
    KOFF(tn, aoffn, boffn);

    // P1
    #pragma unroll
    for (int i = 0; i < 4; ++i) { RD_B(b47[i], cur, 0, 4 + i); }
    STAGE_A(nxt, 0, aoffn);
    asm volatile("s_waitcnt lgkmcnt(4)" ::: "memory");
    __builtin_amdgcn_sched_barrier(0);
    MFMA16(a0, b03, 0);

    // P2
    STAGE_B(nxt, 0, boffn);
    asm volatile("s_waitcnt vmcnt(4)" ::: "memory");
    __builtin_amdgcn_s_barrier();
    asm volatile("" ::: "memory");
    #pragma unroll
    for (int i = 0; i < 4; ++i) { RD_A(a1[i], cur, 1, i); }
    #pragma unroll
    for (int i = 0; i < 4; ++i) { RD_B(b03[i], cur, 1, i); }
    asm volatile("s_waitcnt lgkmcnt(8)" ::: "memory");
    __builtin_amdgcn_sched_barrier(0);
    MFMA16(a0, b47, 4);

    // P3
    #pragma unroll
    for (int i = 0; i < 4; ++i) { RD_B(b47[i], cur, 1, 4 + i); }
    STAGE_A(nxt, 1, aoffn);
    asm volatile("s_waitcnt lgkmcnt(4)" ::: "memory");
    __builtin_amdgcn_sched_barrier(0);
    MFMA16(a1, b03, 0);

    // P4
    STAGE_B(nxt, 1, boffn);
    asm volatile("s_waitcnt vmcnt(4)" ::: "memory");
    __builtin_amdgcn_s_barrier();
    asm volatile("" ::: "memory");
    #pragma unroll
    for (int i = 0; i < 4; ++i) { RD_A(a0[i], nxt, 0, i); }
    #pragma unroll
    for (int i = 0; i < 4; ++i) { RD_B(b03[i], nxt, 0, i); }
    asm volatile("s_waitcnt lgkmcnt(8)" ::: "memory");
    __builtin_amdgcn_sched_barrier(0);
    MFMA16(a1, b47, 4);
  }

  asm volatile("s_waitcnt vmcnt(0) lgkmcnt(0)" ::: "memory");

  const int rowoff = col16 * 4;

  if (bx < 2) {
    // ---- fxT epilogue (unchanged) ----
    #pragma unroll
    for (int mf = 0; mf < 4; ++mf) {
      const int nr = n00 + wm * 64 + mf * 16 + rowoff;
      #pragma unroll
      for (int nf = 0; nf < 8; ++nf) {
        const int co = co00 + wn * 128 + nf * 16 + arow;
        const float bvs = bias[co];
        const float v0 = acc[mf][nf][0] + bvs;
        const float v1 = acc[mf][nf][1] + bvs;
        const float v2 = acc[mf][nf][2] + bvs;
        const float v3 = acc[mf][nf][3] + bvs;
        const int h = co >> 6, c = co & 63;
        unsigned short* dst = fxT + ((int64_t)((b * NH + h) * 64 + c)) * NPAD + nr;
        if (nr + 3 < NN) {
          ushort4_t o; o.x = f2bf(v0); o.y = f2bf(v1); o.z = f2bf(v2); o.w = f2bf(v3);
          *(ushort4_t*)dst = o;
        } else {
          if (nr + 0 < NN) dst[0] = f2bf(v0);
          if (nr + 1 < NN) dst[1] = f2bf(v1);
          if (nr + 2 < NN) dst[2] = f2bf(v2);
          if (nr + 3 < NN) dst[3] = f2bf(v3);
        }
      }
    }
  } else {
    // ---- FUSED eig epilogue v2: coalesced stores via egt[g][n] LDS ----
    const int hbase = (bx - 2) * 4;
    // region per wn: 36864 elems. Phase A layout xm[n(256)][72]; Phase B layout egt[g(64)][264].
    unsigned short* xmw = lds + wn * 36864;
    unsigned short* egw = lds + wn * 36864;
    #pragma unroll 1
    for (int hh = 0; hh < 2; ++hh) {
      __syncthreads();   // prior egt fully consumed / K-loop reads done (iter 0)
      // stage xmid (acc+bias -> bf16), wave-local rows & full d of head hg
      #pragma unroll
      for (int mf = 0; mf < 4; ++mf) {
        const int nr = wm * 64 + mf * 16 + rowoff;
        #pragma unroll
        for (int j = 0; j < 4; ++j) {
          const int nf = hh * 4 + j;
          const int co = co00 + wn * 128 + nf * 16 + arow;
          const float bvs = bias[co];
          const int d = j * 16 + arow;
          #pragma unroll
          for (int r2 = 0; r2 < 4; ++r2)
            xmw[(nr + r2) * 72 + d] = f2bf(acc[mf][nf][r2] + bvs);
        }
      }
      // logits MFMA (wave-local: reads only this wave's rows, written above)
      const int hg = hbase + wn * 2 + hh;
      float tv = temperature[hg];
      tv = fminf(fmaxf(tv, 0.1f), 5.0f);
      const float itemp = 1.0f / tv;
      f32x4 acc2[4][4] = {};
      #pragma unroll
      for (int kk = 0; kk < 2; ++kk) {
        bf16x8 av2[4], bv2[4];
        #pragma unroll
        for (int mg = 0; mg < 4; ++mg)
          av2[mg] = *(const bf16x8*)(xmw + (wm * 64 + mg * 16 + arow) * 72 + kk * 32 + col16 * 8);
        #pragma unroll
        for (int ng = 0; ng < 4; ++ng)
          bv2[ng] = *(const bf16x8*)(gwb + (ng * 16 + arow) * 64 + kk * 32 + col16 * 8);
        #pragma unroll
        for (int mg = 0; mg < 4; ++mg)
          #pragma unroll
          for (int ng = 0; ng < 4; ++ng)
            acc2[mg][ng] = __builtin_amdgcn_mfma_f32_16x16x32_bf16(av2[mg], bv2[ng], acc2[mg][ng], 0, 0, 0);
      }
      __syncthreads();   // all waves' xm reads done before egt overwrite
      // softmax per row -> egt[g][264]
      #pragma unroll
      for (int mg = 0; mg < 4; ++mg) {
        #pragma unroll
        for (int r2 = 0; r2 < 4; ++r2) {
          const int nl = wm * 64 + mg * 16 + rowoff + r2;
          const int n = n00 + nl;
          float vals[4];
          #pragma unroll
          for (int ng = 0; ng < 4; ++ng)
            vals[ng] = (acc2[mg][ng][r2] + gateb[ng * 16 + arow]) * itemp;
          float mx = fmaxf(fmaxf(vals[0], vals[1]), fmaxf(vals[2], vals[3]));
          #pragma unroll
          for (int s = 1; s < 16; s <<= 1) mx = fmaxf(mx, __shfl_xor(mx, s));
          float ex[4]; float sum = 0.f;
          #pragma unroll
          for (int ng = 0; ng < 4; ++ng) { ex[ng] = __expf(vals[ng] - mx); sum += ex[ng]; }
          #pragma unroll
          for (int s = 1; s < 16; s <<= 1) sum += __shfl_xor(sum, s);
          const float inv = 1.0f / sum;
          const bool valid = (n < NN);
          #pragma unroll
          for (int ng = 0; ng < 4; ++ng) {
            const int g = ng * 16 + arow;
            float iv = valid ? inver[(int64_t)n * GG + g] : 0.f;
            unsigned short u = valid ? f2bf(ex[ng] * inv * iv) : (unsigned short)0;
            egw[g * 264 + nl] = u;
          }
        }
      }
      __syncthreads();   // egt complete block-wide
      // eigT: per g-row, 4 segs of 64 n -> 8x ushort8 (128B contiguous runs)
      {
        const int wn2 = tid >> 8;
        const int rest = tid & 255;
        const int g = rest >> 2, seg = rest & 3;
        const int nbase = n00 + seg * 64;
        if (nbase + 63 < NPAD) {
          const int hg2 = hbase + wn2 * 2 + hh;
          const unsigned short* src = lds + wn2 * 36864 + g * 264 + seg * 64;
          unsigned short* dst = eigT + ((int64_t)((b * NH + hg2) * 64 + g)) * NPAD + nbase;
          #pragma unroll
          for (int c0 = 0; c0 < 8; ++c0)
            *(ushort8_t*)(dst + c0 * 8) = *(const ushort8_t*)(src + c0 * 8);
        }
      }
      // eigN: per n-row, gather 64 g (conflict-free scalar LDS reads) -> 128B store
      {
        const int wn2 = tid >> 8;
        const int nl = tid & 255;
        const int n = n00 + nl;
        if (n < NPAD) {
          const int hg2 = hbase + wn2 * 2 + hh;
          const unsigned short* src = lds + wn2 * 36864 + nl;
          unsigned short* dst = eigN + ((int64_t)(b * NH + hg2) * NPAD + n) * 64;
          #pragma unroll
          for (int c0 = 0; c0 < 8; ++c0) {
            ushort8_t v;
            #pragma unroll
            for (int j = 0; j < 8; ++j) v[j] = src[(c0 * 8 + j) * 264];
            *(ushort8_t*)(dst + c0 * 8) = v;
          }
        }
      }
    }
  }
#undef STAGE_A
#undef STAGE_B
#undef KOFF
#undef RD_A
#undef RD_B
#undef MFMA16
}

// ---------------- K4: fused spec-GEMM + LayerNorm + (LN(spec) @ P_h) -> m2t ------------
__launch_bounds__(256, 1)
__global__ void k_specln(const unsigned short* __restrict__ eigT,
                         const unsigned short* __restrict__ fxT,
                         const float* __restrict__ gamma, const float* __restrict__ beta,
                         const unsigned short* __restrict__ Pt,
                         unsigned short* __restrict__ m2t) {
  extern __shared__ char sm[];
  float* sacc = (float*)sm;                                   // [4][64][65] f32
  unsigned short* specb = (unsigned short*)(sm + 66560);      // [64][64] bf16 swz
  float* red = (float*)(sm + 74752);
  unsigned short* mstrip = (unsigned short*)(sm + 74784);     // [4][64][72] u16
  const int bhl = blockIdx.x;
  const int h = bhl & 7, bl = bhl >> 3;
  const int tid = threadIdx.x, w = tid >> 6, lane = tid & 63;
  const int arow = lane & 15, col16 = lane >> 4;
  const int koff = col16 * 8;
  const unsigned short* eb = eigT + (int64_t)bhl * 64 * NPAD;
  const unsigned short* fb = fxT + (int64_t)bhl * 64 * NPAD;

  const int ks0 = (98 * w) >> 2, ks1 = (98 * (w + 1)) >> 2;
  f32x4 acc[4][4] = {};
  for (int ks = ks0; ks < ks1; ++ks) {
    const int k0 = ks * 32 + koff;
    bf16x8 av[4], bv[4];
    #pragma unroll
    for (int mg = 0; mg < 4; ++mg) av[mg] = *(const bf16x8*)(eb + (int64_t)(mg * 16 + arow) * NPAD + k0);
    #pragma unroll
    for (int ng = 0; ng < 4; ++ng) bv[ng] = *(const bf16x8*)(fb + (int64_t)(ng * 16 + arow) * NPAD + k0);
    #pragma unroll
    for (int mg = 0; mg < 4; ++mg)
      #pragma unroll
      for (int ng = 0; ng < 4; ++ng)
        acc[mg][ng] = __builtin_amdgcn_mfma_f32_16x16x32_bf16(av[mg], bv[ng], acc[mg][ng], 0, 0, 0);
  }
  float* pw = sacc + w * (64 * 65);
  #pragma unroll
  for (int mg = 0; mg < 4; ++mg)
    #pragma unroll
    for (int ng = 0; ng < 4; ++ng)
      #pragma unroll
      for (int r = 0; r < 4; ++r)
        pw[(mg * 16 + col16 * 4 + r) * 65 + ng * 16 + arow] = acc[mg][ng][r];
  __syncthreads();

  float vloc[16];
  float lsum = 0.f, lsq = 0.f;
  #pragma unroll
  for (int idx = 0; idx < 16; ++idx) {
    const int e = tid + idx * 256;
    const int g = e >> 6, c = e & 63;
    float v = sacc[g * 65 + c] + sacc[4160 + g * 65 + c] +
              sacc[8320 + g * 65 + c] + sacc[12480 + g * 65 + c];
    vloc[idx] = v; lsum += v; lsq += v * v;
  }
  #pragma unroll
  for (int s = 1; s < 64; s <<= 1) { lsum += __shfl_xor(lsum, s); lsq += __shfl_xor(lsq, s); }
  if (lane == 0) { red[w] = lsum; red[4 + w] = lsq; }
  __syncthreads();
  const float tsum = red[0] + red[1] + red[2] + red[3];
  const float tsq = red[4] + red[5] + red[6] + red[7];
  const float mu = tsum * (1.0f / 4096.0f);
  const float var = tsq * (1.0f / 4096.0f) - mu * mu;
  const float rs = rsqrtf(var + 1e-5f);
  #pragma unroll
  for (int idx = 0; idx < 16; ++idx) {
    const int e = tid + idx * 256;
    const int g = e >> 6, c = e & 63;
    float sv = (vloc[idx] - mu) * rs * gamma[e] + beta[e];
    specb[g * 64 + ((((c >> 3) ^ (g & 7))) << 3) + (c & 7)] = f2bf(sv);
  }
  __syncthreads();

  f32x4 a2[4][4] = {};
  const unsigned short* pth = Pt + ((int64_t)h * 256 + w * 64) * 64;
  #pragma unroll
  for (int kk = 0; kk < 2; ++kk) {
    const int i0 = kk * 32 + koff;
    const int i8 = (i0 >> 3);
    bf16x8 av2[4], bv2[4];
    #pragma unroll
    for (int mg = 0; mg < 4; ++mg) {
      const int g = mg * 16 + arow;
      av2[mg] = *(const bf16x8*)(specb + g * 64 + ((i8 ^ (g & 7)) << 3));
    }
    #pragma unroll
    for (int ng = 0; ng < 4; ++ng)
      bv2[ng] = *(const bf16x8*)(pth + (ng * 16 + arow) * 64 + i0);
    #pragma unroll
    for (int mg = 0; mg < 4; ++mg)
      #pragma unroll
      for (int ng = 0; ng < 4; ++ng)
        a2[mg][ng] = __builtin_amdgcn_mfma_f32_16x16x32_bf16(av2[mg], bv2[ng], a2[mg][ng], 0, 0, 0);
  }
  unsigned short* ms = mstrip + w * (64 * 72);
  #pragma unroll
  for (int mg = 0; mg < 4; ++mg)
    #pragma unroll
    for (int ng = 0; ng < 4; ++ng)
      #pragma unroll
      for (int r = 0; r < 4; ++r)
        ms[(ng * 16 + arow) * 72 + mg * 16 + col16 * 4 + r] = f2bf(a2[mg][ng][r]);
  __syncthreads();
  #pragma unroll
  for (int e0 = 0; e0 < 8; ++e0) {
    const int e = lane + e0 * 64;
    const int row = e >> 3, g8 = e & 7;
    ushort8_t v = *(ushort8_t*)&ms[row * 72 + g8 * 8];
    *(ushort8_t*)(m2t + ((int64_t)(bl * 256 + w * 64 + row)) * 512 + h * 64 + g8 * 8) = v;
  }
}

// ---------------- K5: final out GEMM ----------------
__launch_bounds__(256)
__global__ void k_out(const unsigned short* __restrict__ eigN,
                      const unsigned short* __restrict__ m2t,
                      const float* __restrict__ outb,
                      float* __restrict__ out, int b0) {
  const int swz = xcd_swz(blockIdx.x, gridDim.x);
  const int ct = swz & 1;
  const int mt = (swz >> 1) % 25;
  const int b  = swz / 50;
  const int w = threadIdx.x >> 6, lane = threadIdx.x & 63;
  const int wm = w >> 1, wn = w & 1;
  const int arow = lane & 15, koff = (lane >> 4) * 8;
  const int co0 = ct * 128 + wn * 64;
  const int n0 = mt * 128 + wm * 64;
  f32x4 acc[4][4] = {};
  const unsigned short* ebase = eigN + (int64_t)b * NH * NPAD * 64;
  const unsigned short* mbase = m2t + (int64_t)b * 256 * 512;
  for (int ks = 0; ks < 16; ++ks) {
    const int hh = ks >> 1;
    const int g0 = (ks & 1) * 32 + koff;
    bf16x8 av[4], bv[4];
    #pragma unroll
    for (int mg = 0; mg < 4; ++mg) {
      int n = n0 + mg * 16 + arow;
      if (n > NPAD - 1) n = NPAD - 1;
      av[mg] = *(const bf16x8*)(ebase + ((int64_t)hh * NPAD + n) * 64 + g0);
    }
    #pragma unroll
    for (int ng = 0; ng < 4; ++ng)
      bv[ng] = *(const bf16x8*)(mbase + (int64_t)(co0 + ng * 16 + arow) * 512 + ks * 32 + koff);
    #pragma unroll
    for (int mg = 0; mg < 4; ++mg)
      #pragma unroll
      for (int ng = 0; ng < 4; ++ng)
        acc[mg][ng] = __builtin_amdgcn_mfma_f32_16x16x32_bf16(av[mg], bv[ng], acc[mg][ng], 0, 0, 0);
  }
  #pragma unroll
  for (int mg = 0; mg < 4; ++mg) {
    const int nr = n0 + mg * 16 + ((lane >> 4) << 2);
    #pragma unroll
    for (int ng = 0; ng < 4; ++ng) {
      const int co = co0 + ng * 16 + arow;
      const float bv = outb[co];
      #pragma unroll
      for (int r = 0; r < 4; ++r) {
        if (nr + r < NN)
          out[((int64_t)(b0 + b) * NN + nr + r) * 256 + co] = acc[mg][ng][r] + bv;
      }
    }
  }
}

extern "C" void kernel_launch(void* const* d_in, const int* in_sizes, int n_in,
                              void* d_out, int out_size, void* d_ws, size_t ws_size,
                              hipStream_t stream) {
  const float* x     = (const float*)d_in[0];
  const float* fxw   = (const float*)d_in[1];
  const float* fxb   = (const float*)d_in[2];
  const float* xw    = (const float*)d_in[3];
  const float* xb    = (const float*)d_in[4];
  const float* gw    = (const float*)d_in[5];
  const float* gb    = (const float*)d_in[6];
  const float* temp  = (const float*)d_in[7];
  const float* gamma = (const float*)d_in[8];
  const float* beta  = (const float*)d_in[9];
  const float* mlp   = (const float*)d_in[10];
  const float* outw  = (const float*)d_in[11];
  const float* outb  = (const float*)d_in[12];
  const float* inver = (const float*)d_in[13];
  float* out = (float*)d_out;
  char* ws = (char*)d_ws;
  (void)in_sizes; (void)n_in; (void)out_size;

  hipFuncSetAttribute(reinterpret_cast<const void*>(k_conv8),
                      hipFuncAttributeMaxDynamicSharedMemorySize, 131072);
  hipFuncSetAttribute(reinterpret_cast<const void*>(k_specln),
                      hipFuncAttributeMaxDynamicSharedMemorySize, 131072);

  // CB capped at 16: CB=32 makes each XCD's contiguous chunk span 4 batches ->
  // A-panels + Wb exceed 4MB L2 -> FETCH 88->458MB (measured R10).
  int CB = 1;
  {
    const int cands[5] = {16, 8, 4, 2, 1};
    for (int i = 0; i < 5; ++i) {
      unsigned long long need = 4993024ull + (unsigned long long)cands[i] * 11636224ull;
      if (need <= (unsigned long long)ws_size) { CB = cands[i]; break; }
    }
  }

  unsigned short* Wb   = (unsigned short*)(ws + 0);
  float*          bias = (float*)(ws + 4718592);
  unsigned short* gwb  = (unsigned short*)(ws + 4722688);
  unsigned short* Pt   = (unsigned short*)(ws + 4730880);
  const size_t F0      = 4993024;
  const size_t szXpad  = (size_t)CB * 1740288;
  const size_t szM2t   = (size_t)CB * 262144;
  const size_t szBig   = (size_t)CB * 3211264;
  unsigned short* xpad = (unsigned short*)(ws + F0);
  unsigned short* m2t  = (unsigned short*)(ws + F0 + szXpad);
  unsigned short* fxT  = (unsigned short*)(ws + F0 + szXpad + szM2t);
  unsigned short* eigT = (unsigned short*)(ws + F0 + szXpad + szM2t + szBig);
  unsigned short* eigN = (unsigned short*)(ws + F0 + szXpad + szM2t + 2 * szBig);

  k_wpack<<<dim3(9216), dim3(256), 0, stream>>>(fxw, xw, fxb, xb, gw, Wb, bias, gwb);
  k_pprep<<<dim3(512), dim3(256), 0, stream>>>(mlp, outw, Pt);

  for (int b0 = 0; b0 < BB; b0 += CB) {
    k_pad<<<dim3(WP, HP, CB), dim3(64), 0, stream>>>(x, xpad, b0);
    k_padzero<<<dim3(CB * 10), dim3(256), 0, stream>>>(fxT, CB);
    k_conv8<<<dim3(52 * CB), dim3(512), 131072, stream>>>(xpad, Wb, bias, gwb, gb, temp,
                                                          inver, fxT, eigT, eigN);
    k_specln<<<dim3(CB * 8), dim3(256), 111648, stream>>>(eigT, fxT, gamma, beta, Pt, m2t);
    k_out<<<dim3(50 * CB), dim3(256), 0, stream>>>(eigN, m2t, outb, out, b0);
  }
}

// Round 12
// 904.325 us; speedup vs baseline: 1.4494x; 1.4494x over previous
//
#include <hip/hip_runtime.h>
#include <hip/hip_bf16.h>
#include <stdint.h>

#define HH 101
#define WW 31
#define NN 3131
#define NPAD 3136
#define BB 32
#define NH 8
#define CDIM 256
#define GG 64
#define HP 103
#define WP 33

typedef __attribute__((ext_vector_type(8))) short bf16x8;
typedef __attribute__((ext_vector_type(4))) float f32x4;
typedef __attribute__((ext_vector_type(4))) unsigned short ushort4_t;
typedef __attribute__((ext_vector_type(8))) unsigned short ushort8_t;
typedef __attribute__((ext_vector_type(4))) float float4_t;

static __device__ __forceinline__ unsigned short f2bf(float f) {
  union { float f; uint32_t u; } v; v.f = f;
  uint32_t u = v.u;
  return (unsigned short)((u + 0x7fffu + ((u >> 16) & 1u)) >> 16);
}
static __device__ __forceinline__ float bf2f(unsigned short h) {
  union { uint32_t u; float f; } v; v.u = ((uint32_t)h) << 16;
  return v.f;
}
static __device__ __forceinline__ void gload_lds16(const void* g, void* l) {
  __builtin_amdgcn_global_load_lds((const __attribute__((address_space(1))) void*)g,
                                   (__attribute__((address_space(3))) void*)l, 16, 0, 0);
}
// m204 bijective XCD swizzle
static __device__ __forceinline__ int xcd_swz(int bid, int nwg) {
  int q = nwg >> 3, r = nwg & 7;
  int xcd = bid & 7, pos = bid >> 3;
  int base = (xcd < r) ? xcd * (q + 1) : r * (q + 1) + (xcd - r) * q;
  return base + pos;
}

// ---------------- K0: pad + cast x -> bf16 (CB, HP, WP, C) ----------------
__global__ void k_pad(const float* __restrict__ x, unsigned short* __restrict__ xpad, int b0) {
  const int xx = blockIdx.x, yy = blockIdx.y, b = blockIdx.z;
  const int t = threadIdx.x;
  ushort4_t o; o.x = 0; o.y = 0; o.z = 0; o.w = 0;
  if (yy >= 1 && yy <= HH && xx >= 1 && xx <= WW) {
    const int n = (yy - 1) * WW + (xx - 1);
    const float4_t v = *(const float4_t*)(x + (((int64_t)(b0 + b) * NN + n) * CDIM + t * 4));
    o.x = f2bf(v.x); o.y = f2bf(v.y); o.z = f2bf(v.z); o.w = f2bf(v.w);
  }
  *(ushort4_t*)(xpad + (((int64_t)b * HP + yy) * WP + xx) * CDIM + t * 4) = o;
}

// ---------------- K1: pack conv weights, bias, gate_w ----------------
__global__ void k_wpack(const float* __restrict__ fxw, const float* __restrict__ xw,
                        const float* __restrict__ fxb, const float* __restrict__ xb,
                        const float* __restrict__ gw,
                        unsigned short* __restrict__ Wb, float* __restrict__ bias,
                        unsigned short* __restrict__ gwb) {
  int tid = blockIdx.x * blockDim.x + threadIdx.x;
  const int total = 9 * 1024 * 256;
  if (tid < total) {
    int cin = tid & 255; int rest = tid >> 8; int co = rest & 1023; int t = rest >> 10;
    float v = (co < 512) ? fxw[(int64_t)co * 2304 + cin * 9 + t]
                         : xw[(int64_t)(co - 512) * 2304 + cin * 9 + t];
    Wb[tid] = f2bf(v);
  }
  if (tid < 1024) bias[tid] = (tid < 512) ? fxb[tid] : xb[tid - 512];
  if (tid < 4096) gwb[tid] = f2bf(gw[tid]);
}

// ---------------- K1b: Pt[h][co][i] = sum_c mlp_w[i][c] * out_w[co][h*64+c] (bf16) --------
__global__ void k_pprep(const float* __restrict__ mlp, const float* __restrict__ outw,
                        unsigned short* __restrict__ Pt) {
  int h = blockIdx.x >> 6, i = blockIdx.x & 63, co = threadIdx.x;
  float a = 0.f;
  for (int c = 0; c < 64; ++c) a += mlp[i * 64 + c] * outw[(int64_t)co * 512 + h * 64 + c];
  Pt[((int64_t)h * 256 + co) * 64 + i] = f2bf(a);
}

// ---------------- K1c: zero pad tails of fxT (cols) and xmid (rows) ----------
__global__ void k_padzero(unsigned short* __restrict__ fxT, unsigned short* __restrict__ xmid,
                          int CB) {
  int tid = blockIdx.x * blockDim.x + threadIdx.x;
  if (tid >= CB * 2560) return;
  {
    int j = tid % 5; int rc = tid / 5;
    fxT[(int64_t)rc * NPAD + NN + j] = 0;
  }
  {
    int d = tid & 63; int rest = tid >> 6;
    int j = rest % 5; int bh = rest / 5;
    xmid[((int64_t)bh * NPAD + NN + j) * 64 + d] = 0;
  }
}

// ---------------- K2: 128x256 conv, 4 waves (64x128 each), 2 blocks/CU ----------------
// BK=32 (72 steps), 3 LDS buffers x 24KB = 72KB -> 2 blocks/CU co-resident: the two
// blocks' barrier domains interleave LDS-phase vs MFMA-phase (m114 overlap mechanism).
// Prefetch depth 2, entry vmcnt(6) counted (never 0 mid-loop). T2 swizzle as before.
__launch_bounds__(256, 2)
__global__ void k_conv8(const unsigned short* __restrict__ xpad,
                        const unsigned short* __restrict__ Wb,
                        const float* __restrict__ bias,
                        unsigned short* __restrict__ fxT,
                        unsigned short* __restrict__ xmid) {
  extern __shared__ unsigned short lds[];   // 3 buffers x 12288 elems (A 4096 + B 8192)
  const int swz = xcd_swz(blockIdx.x, gridDim.x);
  const int r   = swz % 100;
  const int b   = swz / 100;
  const int bx  = r & 3;
  const int mt  = r >> 2;                    // 0..24, BM=128
  const int tid = threadIdx.x, wid = tid >> 6, lane = tid & 63;
  const int wm = wid >> 1, wn = wid & 1;     // 2M x 2N waves, wave tile 64x128
  const int arow = lane & 15, col16 = lane >> 4;
  const int n00 = mt * 128, co00 = bx * 256;

  // staging lane maps; source 16B-unit inverse-swizzled (unit ^ ((row>>1)&3) = lane>>3 pattern)
  const int tc = ((lane & 3) ^ ((lane >> 3) & 3)) * 8;
  // A: 2 instrs/thread, rows (wid*2+i)*16 + lane>>2
  const unsigned short* aS[2];
  #pragma unroll
  for (int i = 0; i < 2; ++i) {
    const int srow = (wid * 2 + i) * 16 + (lane >> 2);
    int na = n00 + srow; if (na >= NN) na = NN - 1;
    const int y = na / WW, xv = na % WW;
    aS[i] = xpad + ((int64_t)(b * HP + y) * WP + xv) * CDIM + tc;
  }
  // B: 4 instrs/thread, rows (wid*4+i)*16 + lane>>2
  const unsigned short* bS[4];
  #pragma unroll
  for (int i = 0; i < 4; ++i) {
    const int srow = (wid * 4 + i) * 16 + (lane >> 2);
    bS[i] = Wb + (int64_t)(co00 + srow) * CDIM + tc;
  }

  const int rdsz = (col16 ^ ((arow >> 1) & 3)) * 8;

  f32x4 acc[4][8] = {};

#define STAGE(s, aoffv, boffv)                                        \
  { unsigned short* dA = lds + (s) * 12288 + wid * 1024;              \
    gload_lds16(aS[0] + (aoffv), dA);                                 \
    gload_lds16(aS[1] + (aoffv), dA + 512);                           \
    unsigned short* dB = lds + (s) * 12288 + 4096 + wid * 2048;       \
    gload_lds16(bS[0] + (boffv), dB);                                 \
    gload_lds16(bS[1] + (boffv), dB + 512);                           \
    gload_lds16(bS[2] + (boffv), dB + 1024);                          \
    gload_lds16(bS[3] + (boffv), dB + 1536); }
#define KOFF(ks, aoffv, boffv)                              \
  { const int tap = (ks) >> 3;                              \
    const int dy = (tap >= 6) + (tap >= 3);                 \
    const int dx = tap - dy * 3;                            \
    const int cb = ((ks) & 7) << 5;                         \
    aoffv = (dy * WP + dx) * CDIM + cb;                     \
    boffv = tap * 262144 + cb; }

  // prologue: stage K-steps 0,1 into buffers 0,1 (12 loads/thread)
  {
    int a0o, b0o, a1o, b1o;
    KOFF(0, a0o, b0o); KOFF(1, a1o, b1o);
    STAGE(0, a0o, b0o);
    STAGE(1, a1o, b1o);
  }
  asm volatile("s_waitcnt vmcnt(6)" ::: "memory");   // buffer 0 complete; buffer 1 in flight
  __builtin_amdgcn_s_barrier();
  asm volatile("" ::: "memory");

  #pragma unroll 1
  for (int t = 0; t < 72; ++t) {
    const int cur = t % 3;
    const int s2  = (t + 2) % 3;
    const int tn  = (t + 2 > 71) ? 71 : t + 2;   // tail: duplicate stage, reads discarded
    int aoffn, boffn;
    KOFF(tn, aoffn, boffn);

    // stage t+2 (depth-2 prefetch)
    STAGE(s2, aoffn, boffn);

    // read fragments of current K-step
    const unsigned short* sA = lds + cur * 12288;
    const unsigned short* sB = sA + 4096;
    bf16x8 av[4], bv[8];
    #pragma unroll
    for (int mf = 0; mf < 4; ++mf)
      av[mf] = *(const bf16x8*)(sA + (wm * 64 + mf * 16 + arow) * 32 + rdsz);
    #pragma unroll
    for (int nf = 0; nf < 8; ++nf)
      bv[nf] = *(const bf16x8*)(sB + (wn * 128 + nf * 16 + arow) * 32 + rdsz);
    asm volatile("s_waitcnt lgkmcnt(0)" ::: "memory");
    __builtin_amdgcn_sched_barrier(0);

    __builtin_amdgcn_s_setprio(1);
    #pragma unroll
    for (int mf = 0; mf < 4; ++mf)
      #pragma unroll
      for (int nf = 0; nf < 8; ++nf)
        acc[mf][nf] = __builtin_amdgcn_mfma_f32_16x16x32_bf16(av[mf], bv[nf], acc[mf][nf], 0, 0, 0);
    __builtin_amdgcn_s_setprio(0);

    // next K-step entry: its buffer (staged 2 iters ago + this iter's 6 newer in flight)
    asm volatile("s_waitcnt vmcnt(6)" ::: "memory");
    __builtin_amdgcn_s_barrier();
    asm volatile("" ::: "memory");
  }

  asm volatile("s_waitcnt vmcnt(0) lgkmcnt(0)" ::: "memory");

  const int rowoff = col16 * 4;
  #pragma unroll
  for (int mf = 0; mf < 4; ++mf) {
    const int nr = n00 + wm * 64 + mf * 16 + rowoff;
    #pragma unroll
    for (int nf = 0; nf < 8; ++nf) {
      const int co = co00 + wn * 128 + nf * 16 + arow;
      const float bvs = bias[co];
      const float v0 = acc[mf][nf][0] + bvs;
      const float v1 = acc[mf][nf][1] + bvs;
      const float v2 = acc[mf][nf][2] + bvs;
      const float v3 = acc[mf][nf][3] + bvs;
      if (bx < 2) {
        const int h = co >> 6, c = co & 63;
        unsigned short* dst = fxT + ((int64_t)((b * NH + h) * 64 + c)) * NPAD + nr;
        if (nr + 3 < NN) {
          ushort4_t o; o.x = f2bf(v0); o.y = f2bf(v1); o.z = f2bf(v2); o.w = f2bf(v3);
          *(ushort4_t*)dst = o;
        } else {
          if (nr + 0 < NN) dst[0] = f2bf(v0);
          if (nr + 1 < NN) dst[1] = f2bf(v1);
          if (nr + 2 < NN) dst[2] = f2bf(v2);
          if (nr + 3 < NN) dst[3] = f2bf(v3);
        }
      } else {
        const int h = (co >> 6) & 7, d = co & 63;
        unsigned short* dst = xmid + ((int64_t)(b * NH + h) * NPAD + nr) * 64 + d;
        if (nr + 0 < NN) dst[0] = f2bf(v0);
        if (nr + 1 < NN) dst[64] = f2bf(v1);
        if (nr + 2 < NN) dst[128] = f2bf(v2);
        if (nr + 3 < NN) dst[192] = f2bf(v3);
      }
    }
  }
#undef STAGE
#undef KOFF
}

// ---------------- K3: logits MFMA + softmax + eigens; LDS-staged coalesced stores -------
__global__ void k_eig(const unsigned short* __restrict__ xmid,
                      const unsigned short* __restrict__ gwb,
                      const float* __restrict__ gateb,
                      const float* __restrict__ temperature,
                      const float* __restrict__ inver,
                      unsigned short* __restrict__ eigT,
                      unsigned short* __restrict__ eigN) {
  __shared__ unsigned short egN[64 * 72];
  __shared__ unsigned short egT[64 * 72];
  const int nt = blockIdx.x, h = blockIdx.y, b = blockIdx.z;
  const int tid = threadIdx.x;
  const int w = tid >> 6, lane = tid & 63;
  const int n0 = nt * 64 + w * 16;
  const int bh = b * NH + h;
  float tv = temperature[h];
  tv = fminf(fmaxf(tv, 0.1f), 5.0f);
  const float itemp = 1.0f / tv;
  const int arow = lane & 15;
  const int koff = (lane >> 4) * 8;
  const unsigned short* aptr = xmid + ((int64_t)bh * NPAD + (n0 + arow)) * 64 + koff;
  bf16x8 a0 = *(const bf16x8*)(aptr);
  bf16x8 a1 = *(const bf16x8*)(aptr + 32);
  f32x4 acc[4] = {};
  #pragma unroll
  for (int ng = 0; ng < 4; ++ng) {
    const unsigned short* bptr = gwb + (ng * 16 + arow) * 64 + koff;
    bf16x8 b0 = *(const bf16x8*)(bptr);
    bf16x8 b1 = *(const bf16x8*)(bptr + 32);
    acc[ng] = __builtin_amdgcn_mfma_f32_16x16x32_bf16(a0, b0, acc[ng], 0, 0, 0);
    acc[ng] = __builtin_amdgcn_mfma_f32_16x16x32_bf16(a1, b1, acc[ng], 0, 0, 0);
  }
  #pragma unroll
  for (int r = 0; r < 4; ++r) {
    const int nl = w * 16 + ((lane >> 4) << 2) + r;
    const int n = nt * 64 + nl;
    float vals[4];
    #pragma unroll
    for (int ng = 0; ng < 4; ++ng) vals[ng] = (acc[ng][r] + gateb[ng * 16 + arow]) * itemp;
    float mx = fmaxf(fmaxf(vals[0], vals[1]), fmaxf(vals[2], vals[3]));
    #pragma unroll
    for (int s = 1; s < 16; s <<= 1) mx = fmaxf(mx, __shfl_xor(mx, s));
    float ex[4]; float sum = 0.f;
    #pragma unroll
    for (int ng = 0; ng < 4; ++ng) { ex[ng] = __expf(vals[ng] - mx); sum += ex[ng]; }
    #pragma unroll
    for (int s = 1; s < 16; s <<= 1) sum += __shfl_xor(sum, s);
    const float inv = 1.0f / sum;
    const bool valid = (n < NN);
    #pragma unroll
    for (int ng = 0; ng < 4; ++ng) {
      const int g = ng * 16 + arow;
      float iv = valid ? inver[(int64_t)n * GG + g] : 0.f;
      unsigned short u = valid ? f2bf(ex[ng] * inv * iv) : (unsigned short)0;
      egN[nl * 72 + g] = u;
      egT[g * 72 + nl] = u;
    }
  }
  __syncthreads();
  const int row = tid >> 2, c0 = (tid & 3) << 4;
  {
    ushort8_t v0 = *(ushort8_t*)&egN[row * 72 + c0];
    ushort8_t v1 = *(ushort8_t*)&egN[row * 72 + c0 + 8];
    unsigned short* dst = eigN + ((int64_t)bh * NPAD + nt * 64 + row) * 64 + c0;
    *(ushort8_t*)dst = v0; *(ushort8_t*)(dst + 8) = v1;
  }
  {
    ushort8_t v0 = *(ushort8_t*)&egT[row * 72 + c0];
    ushort8_t v1 = *(ushort8_t*)&egT[row * 72 + c0 + 8];
    unsigned short* dst = eigT + ((int64_t)(bh * 64 + row)) * NPAD + nt * 64 + c0;
    *(ushort8_t*)dst = v0; *(ushort8_t*)(dst + 8) = v1;
  }
}

// ---------------- K4: fused spec-GEMM + LayerNorm + (LN(spec) @ P_h) -> m2t ------------
__launch_bounds__(256, 1)
__global__ void k_specln(const unsigned short* __restrict__ eigT,
                         const unsigned short* __restrict__ fxT,
                         const float* __restrict__ gamma, const float* __restrict__ beta,
                         const unsigned short* __restrict__ Pt,
                         unsigned short* __restrict__ m2t) {
  extern __shared__ char sm[];
  float* sacc = (float*)sm;                                   // [4][64][65] f32
  unsigned short* specb = (unsigned short*)(sm + 66560);      // [64][64] bf16 swz
  float* red = (float*)(sm + 74752);
  unsigned short* mstrip = (unsigned short*)(sm + 74784);     // [4][64][72] u16
  const int bhl = blockIdx.x;
  const int h = bhl & 7, bl = bhl >> 3;
  const int tid = threadIdx.x, w = tid >> 6, lane = tid & 63;
  const int arow = lane & 15, col16 = lane >> 4;
  const int koff = col16 * 8;
  const unsigned short* eb = eigT + (int64_t)bhl * 64 * NPAD;
  const unsigned short* fb = fxT + (int64_t)bhl * 64 * NPAD;

  const int ks0 = (98 * w) >> 2, ks1 = (98 * (w + 1)) >> 2;
  f32x4 acc[4][4] = {};
  for (int ks = ks0; ks < ks1; ++ks) {
    const int k0 = ks * 32 + koff;
    bf16x8 av[4], bv[4];
    #pragma unroll
    for (int mg = 0; mg < 4; ++mg) av[mg] = *(const bf16x8*)(eb + (int64_t)(mg * 16 + arow) * NPAD + k0);
    #pragma unroll
    for (int ng = 0; ng < 4; ++ng) bv[ng] = *(const bf16x8*)(fb + (int64_t)(ng * 16 + arow) * NPAD + k0);
    #pragma unroll
    for (int mg = 0; mg < 4; ++mg)
      #pragma unroll
      for (int ng = 0; ng < 4; ++ng)
        acc[mg][ng] = __builtin_amdgcn_mfma_f32_16x16x32_bf16(av[mg], bv[ng], acc[mg][ng], 0, 0, 0);
  }
  float* pw = sacc + w * (64 * 65);
  #pragma unroll
  for (int mg = 0; mg < 4; ++mg)
    #pragma unroll
    for (int ng = 0; ng < 4; ++ng)
      #pragma unroll
      for (int r = 0; r < 4; ++r)
        pw[(mg * 16 + col16 * 4 + r) * 65 + ng * 16 + arow] = acc[mg][ng][r];
  __syncthreads();

  float vloc[16];
  float lsum = 0.f, lsq = 0.f;
  #pragma unroll
  for (int idx = 0; idx < 16; ++idx) {
    const int e = tid + idx * 256;
    const int g = e >> 6, c = e & 63;
    float v = sacc[g * 65 + c] + sacc[4160 + g * 65 + c] +
              sacc[8320 + g * 65 + c] + sacc[12480 + g * 65 + c];
    vloc[idx] = v; lsum += v; lsq += v * v;
  }
  #pragma unroll
  for (int s = 1; s < 64; s <<= 1) { lsum += __shfl_xor(lsum, s); lsq += __shfl_xor(lsq, s); }
  if (lane == 0) { red[w] = lsum; red[4 + w] = lsq; }
  __syncthreads();
  const float tsum = red[0] + red[1] + red[2] + red[3];
  const float tsq = red[4] + red[5] + red[6] + red[7];
  const float mu = tsum * (1.0f / 4096.0f);
  const float var = tsq * (1.0f / 4096.0f) - mu * mu;
  const float rs = rsqrtf(var + 1e-5f);
  #pragma unroll
  for (int idx = 0; idx < 16; ++idx) {
    const int e = tid + idx * 256;
    const int g = e >> 6, c = e & 63;
    float sv = (vloc[idx] - mu) * rs * gamma[e] + beta[e];
    specb[g * 64 + ((((c >> 3) ^ (g & 7))) << 3) + (c & 7)] = f2bf(sv);
  }
  __syncthreads();

  f32x4 a2[4][4] = {};
  const unsigned short* pth = Pt + ((int64_t)h * 256 + w * 64) * 64;
  #pragma unroll
  for (int kk = 0; kk < 2; ++kk) {
    const int i0 = kk * 32 + koff;
    const int i8 = (i0 >> 3);
    bf16x8 av2[4], bv2[4];
    #pragma unroll
    for (int mg = 0; mg < 4; ++mg) {
      const int g = mg * 16 + arow;
      av2[mg] = *(const bf16x8*)(specb + g * 64 + ((i8 ^ (g & 7)) << 3));
    }
    #pragma unroll
    for (int ng = 0; ng < 4; ++ng)
      bv2[ng] = *(const bf16x8*)(pth + (ng * 16 + arow) * 64 + i0);
    #pragma unroll
    for (int mg = 0; mg < 4; ++mg)
      #pragma unroll
      for (int ng = 0; ng < 4; ++ng)
        a2[mg][ng] = __builtin_amdgcn_mfma_f32_16x16x32_bf16(av2[mg], bv2[ng], a2[mg][ng], 0, 0, 0);
  }
  unsigned short* ms = mstrip + w * (64 * 72);
  #pragma unroll
  for (int mg = 0; mg < 4; ++mg)
    #pragma unroll
    for (int ng = 0; ng < 4; ++ng)
      #pragma unroll
      for (int r = 0; r < 4; ++r)
        ms[(ng * 16 + arow) * 72 + mg * 16 + col16 * 4 + r] = f2bf(a2[mg][ng][r]);
  __syncthreads();
  #pragma unroll
  for (int e0 = 0; e0 < 8; ++e0) {
    const int e = lane + e0 * 64;
    const int row = e >> 3, g8 = e & 7;
    ushort8_t v = *(ushort8_t*)&ms[row * 72 + g8 * 8];
    *(ushort8_t*)(m2t + ((int64_t)(bl * 256 + w * 64 + row)) * 512 + h * 64 + g8 * 8) = v;
  }
}

// ---------------- K5: final out GEMM ----------------
__launch_bounds__(256)
__global__ void k_out(const unsigned short* __restrict__ eigN,
                      const unsigned short* __restrict__ m2t,
                      const float* __restrict__ outb,
                      float* __restrict__ out, int b0) {
  const int swz = xcd_swz(blockIdx.x, gridDim.x);
  const int ct = swz & 1;
  const int mt = (swz >> 1) % 25;
  const int b  = swz / 50;
  const int w = threadIdx.x >> 6, lane = threadIdx.x & 63;
  const int wm = w >> 1, wn = w & 1;
  const int arow = lane & 15, koff = (lane >> 4) * 8;
  const int co0 = ct * 128 + wn * 64;
  const int n0 = mt * 128 + wm * 64;
  f32x4 acc[4][4] = {};
  const unsigned short* ebase = eigN + (int64_t)b * NH * NPAD * 64;
  const unsigned short* mbase = m2t + (int64_t)b * 256 * 512;
  for (int ks = 0; ks < 16; ++ks) {
    const int hh = ks >> 1;
    const int g0 = (ks & 1) * 32 + koff;
    bf16x8 av[4], bv[4];
    #pragma unroll
    for (int mg = 0; mg < 4; ++mg) {
      int n = n0 + mg * 16 + arow;
      if (n > NPAD - 1) n = NPAD - 1;
      av[mg] = *(const bf16x8*)(ebase + ((int64_t)hh * NPAD + n) * 64 + g0);
    }
    #pragma unroll
    for (int ng = 0; ng < 4; ++ng)
      bv[ng] = *(const bf16x8*)(mbase + (int64_t)(co0 + ng * 16 + arow) * 512 + ks * 32 + koff);
    #pragma unroll
    for (int mg = 0; mg < 4; ++mg)
      #pragma unroll
      for (int ng = 0; ng < 4; ++ng)
        acc[mg][ng] = __builtin_amdgcn_mfma_f32_16x16x32_bf16(av[mg], bv[ng], acc[mg][ng], 0, 0, 0);
  }
  #pragma unroll
  for (int mg = 0; mg < 4; ++mg) {
    const int nr = n0 + mg * 16 + ((lane >> 4) << 2);
    #pragma unroll
    for (int ng = 0; ng < 4; ++ng) {
      const int co = co0 + ng * 16 + arow;
      const float bv = outb[co];
      #pragma unroll
      for (int r = 0; r < 4; ++r) {
        if (nr + r < NN)
          out[((int64_t)(b0 + b) * NN + nr + r) * 256 + co] = acc[mg][ng][r] + bv;
      }
    }
  }
}

extern "C" void kernel_launch(void* const* d_in, const int* in_sizes, int n_in,
                              void* d_out, int out_size, void* d_ws, size_t ws_size,
                              hipStream_t stream) {
  const float* x     = (const float*)d_in[0];
  const float* fxw   = (const float*)d_in[1];
  const float* fxb   = (const float*)d_in[2];
  const float* xw    = (const float*)d_in[3];
  const float* xb    = (const float*)d_in[4];
  const float* gw    = (const float*)d_in[5];
  const float* gb    = (const float*)d_in[6];
  const float* temp  = (const float*)d_in[7];
  const float* gamma = (const float*)d_in[8];
  const float* beta  = (const float*)d_in[9];
  const float* mlp   = (const float*)d_in[10];
  const float* outw  = (const float*)d_in[11];
  const float* outb  = (const float*)d_in[12];
  const float* inver = (const float*)d_in[13];
  float* out = (float*)d_out;
  char* ws = (char*)d_ws;
  (void)in_sizes; (void)n_in; (void)out_size;

  hipFuncSetAttribute(reinterpret_cast<const void*>(k_conv8),
                      hipFuncAttributeMaxDynamicSharedMemorySize, 73728);
  hipFuncSetAttribute(reinterpret_cast<const void*>(k_specln),
                      hipFuncAttributeMaxDynamicSharedMemorySize, 131072);

  // CB capped at 16 (R10 lesson: CB=32 overflows per-XCD L2 working set)
  int CB = 1;
  {
    const int cands[5] = {16, 8, 4, 2, 1};
    for (int i = 0; i < 5; ++i) {
      unsigned long long need = 4993024ull + (unsigned long long)cands[i] * 14847488ull;
      if (need <= (unsigned long long)ws_size) { CB = cands[i]; break; }
    }
  }

  unsigned short* Wb   = (unsigned short*)(ws + 0);
  float*          bias = (float*)(ws + 4718592);
  unsigned short* gwb  = (unsigned short*)(ws + 4722688);
  unsigned short* Pt   = (unsigned short*)(ws + 4730880);
  const size_t F0      = 4993024;
  const size_t szXpad  = (size_t)CB * 1740288;
  const size_t szM2t   = (size_t)CB * 262144;
  const size_t szBig   = (size_t)CB * 3211264;
  unsigned short* xpad = (unsigned short*)(ws + F0);
  unsigned short* m2t  = (unsigned short*)(ws + F0 + szXpad);
  unsigned short* fxT  = (unsigned short*)(ws + F0 + szXpad + szM2t);
  unsigned short* xmid = (unsigned short*)(ws + F0 + szXpad + szM2t + szBig);
  unsigned short* eigT = (unsigned short*)(ws + F0 + szXpad + szM2t + 2 * szBig);
  unsigned short* eigN = (unsigned short*)(ws + F0 + szXpad + szM2t + 3 * szBig);

  k_wpack<<<dim3(9216), dim3(256), 0, stream>>>(fxw, xw, fxb, xb, gw, Wb, bias, gwb);
  k_pprep<<<dim3(512), dim3(256), 0, stream>>>(mlp, outw, Pt);

  for (int b0 = 0; b0 < BB; b0 += CB) {
    k_pad<<<dim3(WP, HP, CB), dim3(64), 0, stream>>>(x, xpad, b0);
    k_padzero<<<dim3(CB * 10), dim3(256), 0, stream>>>(fxT, xmid, CB);
    k_conv8<<<dim3(100 * CB), dim3(256), 73728, stream>>>(xpad, Wb, bias, fxT, xmid);
    k_eig<<<dim3(49, 8, CB), dim3(256), 0, stream>>>(xmid, gwb, gb, temp, inver, eigT, eigN);
    k_specln<<<dim3(CB * 8), dim3(256), 111648, stream>>>(eigT, fxT, gamma, beta, Pt, m2t);
    k_out<<<dim3(50 * CB), dim3(256), 0, stream>>>(eigN, m2t, outb, out, b0);
  }
}

// Round 13
// 889.334 us; speedup vs baseline: 1.4739x; 1.0169x over previous
//
#include <hip/hip_runtime.h>
#include <hip/hip_bf16.h>
#include <stdint.h>

#define HH 101
#define WW 31
#define NN 3131
#define NPAD 3136
#define BB 32
#define NH 8
#define CDIM 256
#define GG 64
#define HP 103
#define WP 33

typedef __attribute__((ext_vector_type(8))) short bf16x8;
typedef __attribute__((ext_vector_type(4))) float f32x4;
typedef __attribute__((ext_vector_type(4))) unsigned short ushort4_t;
typedef __attribute__((ext_vector_type(8))) unsigned short ushort8_t;
typedef __attribute__((ext_vector_type(4))) float float4_t;

static __device__ __forceinline__ unsigned short f2bf(float f) {
  union { float f; uint32_t u; } v; v.f = f;
  uint32_t u = v.u;
  return (unsigned short)((u + 0x7fffu + ((u >> 16) & 1u)) >> 16);
}
static __device__ __forceinline__ float bf2f(unsigned short h) {
  union { uint32_t u; float f; } v; v.u = ((uint32_t)h) << 16;
  return v.f;
}
static __device__ __forceinline__ void gload_lds16(const void* g, void* l) {
  __builtin_amdgcn_global_load_lds((const __attribute__((address_space(1))) void*)g,
                                   (__attribute__((address_space(3))) void*)l, 16, 0, 0);
}
// m204 bijective XCD swizzle
static __device__ __forceinline__ int xcd_swz(int bid, int nwg) {
  int q = nwg >> 3, r = nwg & 7;
  int xcd = bid & 7, pos = bid >> 3;
  int base = (xcd < r) ? xcd * (q + 1) : r * (q + 1) + (xcd - r) * q;
  return base + pos;
}

// ---------------- K0: pad + cast x -> bf16 (CB, HP, WP, C) ----------------
__global__ void k_pad(const float* __restrict__ x, unsigned short* __restrict__ xpad, int b0) {
  const int xx = blockIdx.x, yy = blockIdx.y, b = blockIdx.z;
  const int t = threadIdx.x;
  ushort4_t o; o.x = 0; o.y = 0; o.z = 0; o.w = 0;
  if (yy >= 1 && yy <= HH && xx >= 1 && xx <= WW) {
    const int n = (yy - 1) * WW + (xx - 1);
    const float4_t v = *(const float4_t*)(x + (((int64_t)(b0 + b) * NN + n) * CDIM + t * 4));
    o.x = f2bf(v.x); o.y = f2bf(v.y); o.z = f2bf(v.z); o.w = f2bf(v.w);
  }
  *(ushort4_t*)(xpad + (((int64_t)b * HP + yy) * WP + xx) * CDIM + t * 4) = o;
}

// ---------------- K1: pack conv weights, bias, gate_w ----------------
__global__ void k_wpack(const float* __restrict__ fxw, const float* __restrict__ xw,
                        const float* __restrict__ fxb, const float* __restrict__ xb,
                        const float* __restrict__ gw,
                        unsigned short* __restrict__ Wb, float* __restrict__ bias,
                        unsigned short* __restrict__ gwb) {
  int tid = blockIdx.x * blockDim.x + threadIdx.x;
  const int total = 9 * 1024 * 256;
  if (tid < total) {
    int cin = tid & 255; int rest = tid >> 8; int co = rest & 1023; int t = rest >> 10;
    float v = (co < 512) ? fxw[(int64_t)co * 2304 + cin * 9 + t]
                         : xw[(int64_t)(co - 512) * 2304 + cin * 9 + t];
    Wb[tid] = f2bf(v);
  }
  if (tid < 1024) bias[tid] = (tid < 512) ? fxb[tid] : xb[tid - 512];
  if (tid < 4096) gwb[tid] = f2bf(gw[tid]);
}

// ---------------- K1b: Pt[h][co][i] = sum_c mlp_w[i][c] * out_w[co][h*64+c] (bf16) --------
__global__ void k_pprep(const float* __restrict__ mlp, const float* __restrict__ outw,
                        unsigned short* __restrict__ Pt) {
  int h = blockIdx.x >> 6, i = blockIdx.x & 63, co = threadIdx.x;
  float a = 0.f;
  for (int c = 0; c < 64; ++c) a += mlp[i * 64 + c] * outw[(int64_t)co * 512 + h * 64 + c];
  Pt[((int64_t)h * 256 + co) * 64 + i] = f2bf(a);
}

// ---------------- K1c: zero pad tails of fxT (cols) and xmid (rows) ----------
__global__ void k_padzero(unsigned short* __restrict__ fxT, unsigned short* __restrict__ xmid,
                          int CB) {
  int tid = blockIdx.x * blockDim.x + threadIdx.x;
  if (tid >= CB * 2560) return;
  {
    int j = tid % 5; int rc = tid / 5;
    fxT[(int64_t)rc * NPAD + NN + j] = 0;
  }
  {
    int d = tid & 63; int rest = tid >> 6;
    int j = rest % 5; int bh = rest / 5;
    xmid[((int64_t)bh * NPAD + NN + j) * 64 + d] = 0;
  }
}

// ---------------- K2: 256x256 conv, R7 structure (best measured: 266us, 44% MfmaUtil) ----
// 8 waves 4M x 2N (wave 64x128), BK=64 (36 steps), 2 LDS buffers (128KB),
// reg-pipelined counted waits (vmcnt(4), lgkm(4/8)), never 0 mid-loop.
__launch_bounds__(512, 2)
__global__ void k_conv8(const unsigned short* __restrict__ xpad,
                        const unsigned short* __restrict__ Wb,
                        const float* __restrict__ bias,
                        unsigned short* __restrict__ fxT,
                        unsigned short* __restrict__ xmid) {
  extern __shared__ unsigned short lds[];   // 2 x 32768 elems
  const int swz = xcd_swz(blockIdx.x, gridDim.x);
  const int r   = swz % 52;
  const int b   = swz / 52;
  const int bx  = r & 3;
  const int mt  = r >> 2;
  const int tid = threadIdx.x, wid = tid >> 6, lane = tid & 63;
  const int wm = wid & 3, wn = wid >> 2;           // 4 M-waves x 2 N-waves
  const int arow = lane & 15, col16 = lane >> 4;
  const int n00 = mt * 256, co00 = bx * 256;

  const int srow = wid * 16 + (lane >> 2);
  const int tc   = ((lane & 3) ^ ((lane >> 3) & 3)) * 8;
  int na0 = n00 + srow;        if (na0 >= NN) na0 = NN - 1;
  int na1 = n00 + srow + 128;  if (na1 >= NN) na1 = NN - 1;
  const int y0 = na0 / WW, x0v = na0 % WW;
  const int y1 = na1 / WW, x1v = na1 % WW;
  const unsigned short* aS0 = xpad + ((int64_t)(b * HP + y0) * WP + x0v) * CDIM + tc;
  const unsigned short* aS1 = xpad + ((int64_t)(b * HP + y1) * WP + x1v) * CDIM + tc;
  const unsigned short* bS0 = Wb + (int64_t)(co00 + srow) * CDIM + tc;
  const unsigned short* bS1 = Wb + (int64_t)(co00 + srow + 128) * CDIM + tc;

  const int rdsz = (col16 ^ ((arow >> 1) & 3)) * 8;

  f32x4 acc[4][8] = {};
  bf16x8 a0[4], a1[4], b03[4], b47[4];

#define STAGE_A(s, kk, aoffv)                                        \
  { unsigned short* d = lds + (s) * 32768 + (kk) * 8192 + wid * 512; \
    gload_lds16(aS0 + (aoffv) + (kk) * 32, d);                       \
    gload_lds16(aS1 + (aoffv) + (kk) * 32, d + 4096); }
#define STAGE_B(s, kk, boffv)                                                \
  { unsigned short* d = lds + (s) * 32768 + 16384 + (kk) * 8192 + wid * 512; \
    gload_lds16(bS0 + (boffv) + (kk) * 32, d);                               \
    gload_lds16(bS1 + (boffv) + (kk) * 32, d + 4096); }
#define KOFF(ks, aoffv, boffv)                              \
  { const int tap = (ks) >> 2;                              \
    const int dy = (tap >= 6) + (tap >= 3);                 \
    const int dx = tap - dy * 3;                            \
    const int cb = ((ks) & 3) << 6;                         \
    aoffv = (dy * WP + dx) * CDIM + cb;                     \
    boffv = tap * 262144 + cb; }
#define RD_A(dst, s, kk, mf)                                                             \
  dst = *(const bf16x8*)(lds + (s) * 32768 + (kk) * 8192 +                               \
                         (wm * 64 + (mf) * 16 + arow) * 32 + rdsz);
#define RD_B(dst, s, kk, nf)                                                             \
  dst = *(const bf16x8*)(lds + (s) * 32768 + 16384 + (kk) * 8192 +                       \
                         (wn * 128 + (nf) * 16 + arow) * 32 + rdsz);
#define MFMA16(aset, bset, nbase)                                                        \
  __builtin_amdgcn_s_setprio(1);                                                         \
  _Pragma("unroll")                                                                      \
  for (int mf = 0; mf < 4; ++mf) {                                                       \
    _Pragma("unroll")                                                                    \
    for (int nf = 0; nf < 4; ++nf)                                                       \
      acc[mf][(nbase) + nf] =                                                            \
        __builtin_amdgcn_mfma_f32_16x16x32_bf16(aset[mf], bset[nf], acc[mf][(nbase) + nf], 0, 0, 0); \
  }                                                                                      \
  __builtin_amdgcn_s_setprio(0);

  // ---- prologue ----
  int aoff0, boff0;
  KOFF(0, aoff0, boff0);
  STAGE_A(0, 0, aoff0); STAGE_B(0, 0, boff0);
  STAGE_A(0, 1, aoff0); STAGE_B(0, 1, boff0);
  asm volatile("s_waitcnt vmcnt(4)" ::: "memory");
  __builtin_amdgcn_s_barrier();
  asm volatile("" ::: "memory");
  #pragma unroll
  for (int i = 0; i < 4; ++i) { RD_A(a0[i], 0, 0, i); }
  #pragma unroll
  for (int i = 0; i < 4; ++i) { RD_B(b03[i], 0, 0, i); }

  #pragma unroll 1
  for (int t = 0; t < 36; ++t) {
    const int cur = t & 1, nxt = cur ^ 1;
    const int tn = (t < 35) ? t + 1 : 35;
    int aoffn, boffn;
    KOFF(tn, aoffn, boffn);

    // P1
    #pragma unroll
    for (int i = 0; i < 4; ++i) { RD_B(b47[i], cur, 0, 4 + i); }
    STAGE_A(nxt, 0, aoffn);
    asm volatile("s_waitcnt lgkmcnt(4)" ::: "memory");
    __builtin_amdgcn_sched_barrier(0);
    MFMA16(a0, b03, 0);

    // P2
    STAGE_B(nxt, 0, boffn);
    asm volatile("s_waitcnt vmcnt(4)" ::: "memory");
    __builtin_amdgcn_s_barrier();
    asm volatile("" ::: "memory");
    #pragma unroll
    for (int i = 0; i < 4; ++i) { RD_A(a1[i], cur, 1, i); }
    #pragma unroll
    for (int i = 0; i < 4; ++i) { RD_B(b03[i], cur, 1, i); }
    asm volatile("s_waitcnt lgkmcnt(8)" ::: "memory");
    __builtin_amdgcn_sched_barrier(0);
    MFMA16(a0, b47, 4);

    // P3
    #pragma unroll
    for (int i = 0; i < 4; ++i) { RD_B(b47[i], cur, 1, 4 + i); }
    STAGE_A(nxt, 1, aoffn);
    asm volatile("s_waitcnt lgkmcnt(4)" ::: "memory");
    __builtin_amdgcn_sched_barrier(0);
    MFMA16(a1, b03, 0);

    // P4
    STAGE_B(nxt, 1, boffn);
    asm volatile("s_waitcnt vmcnt(4)" ::: "memory");
    __builtin_amdgcn_s_barrier();
    asm volatile("" ::: "memory");
    #pragma unroll
    for (int i = 0; i < 4; ++i) { RD_A(a0[i], nxt, 0, i); }
    #pragma unroll
    for (int i = 0; i < 4; ++i) { RD_B(b03[i], nxt, 0, i); }
    asm volatile("s_waitcnt lgkmcnt(8)" ::: "memory");
    __builtin_amdgcn_sched_barrier(0);
    MFMA16(a1, b47, 4);
  }

  asm volatile("s_waitcnt vmcnt(0) lgkmcnt(0)" ::: "memory");

  const int rowoff = col16 * 4;
  #pragma unroll
  for (int mf = 0; mf < 4; ++mf) {
    const int nr = n00 + wm * 64 + mf * 16 + rowoff;
    #pragma unroll
    for (int nf = 0; nf < 8; ++nf) {
      const int co = co00 + wn * 128 + nf * 16 + arow;
      const float bvs = bias[co];
      const float v0 = acc[mf][nf][0] + bvs;
      const float v1 = acc[mf][nf][1] + bvs;
      const float v2 = acc[mf][nf][2] + bvs;
      const float v3 = acc[mf][nf][3] + bvs;
      if (bx < 2) {
        const int h = co >> 6, c = co & 63;
        unsigned short* dst = fxT + ((int64_t)((b * NH + h) * 64 + c)) * NPAD + nr;
        if (nr + 3 < NN) {
          ushort4_t o; o.x = f2bf(v0); o.y = f2bf(v1); o.z = f2bf(v2); o.w = f2bf(v3);
          *(ushort4_t*)dst = o;
        } else {
          if (nr + 0 < NN) dst[0] = f2bf(v0);
          if (nr + 1 < NN) dst[1] = f2bf(v1);
          if (nr + 2 < NN) dst[2] = f2bf(v2);
          if (nr + 3 < NN) dst[3] = f2bf(v3);
        }
      } else {
        const int h = (co >> 6) & 7, d = co & 63;
        unsigned short* dst = xmid + ((int64_t)(b * NH + h) * NPAD + nr) * 64 + d;
        if (nr + 0 < NN) dst[0] = f2bf(v0);
        if (nr + 1 < NN) dst[64] = f2bf(v1);
        if (nr + 2 < NN) dst[128] = f2bf(v2);
        if (nr + 3 < NN) dst[192] = f2bf(v3);
      }
    }
  }
#undef STAGE_A
#undef STAGE_B
#undef KOFF
#undef RD_A
#undef RD_B
#undef MFMA16
}

// ---------------- K3: logits MFMA + softmax + eigens; LDS-staged coalesced stores -------
__global__ void k_eig(const unsigned short* __restrict__ xmid,
                      const unsigned short* __restrict__ gwb,
                      const float* __restrict__ gateb,
                      const float* __restrict__ temperature,
                      const float* __restrict__ inver,
                      unsigned short* __restrict__ eigT,
                      unsigned short* __restrict__ eigN) {
  __shared__ unsigned short egN[64 * 72];
  __shared__ unsigned short egT[64 * 72];
  const int nt = blockIdx.x, h = blockIdx.y, b = blockIdx.z;
  const int tid = threadIdx.x;
  const int w = tid >> 6, lane = tid & 63;
  const int n0 = nt * 64 + w * 16;
  const int bh = b * NH + h;
  float tv = temperature[h];
  tv = fminf(fmaxf(tv, 0.1f), 5.0f);
  const float itemp = 1.0f / tv;
  const int arow = lane & 15;
  const int koff = (lane >> 4) * 8;
  const unsigned short* aptr = xmid + ((int64_t)bh * NPAD + (n0 + arow)) * 64 + koff;
  bf16x8 a0 = *(const bf16x8*)(aptr);
  bf16x8 a1 = *(const bf16x8*)(aptr + 32);
  f32x4 acc[4] = {};
  #pragma unroll
  for (int ng = 0; ng < 4; ++ng) {
    const unsigned short* bptr = gwb + (ng * 16 + arow) * 64 + koff;
    bf16x8 b0 = *(const bf16x8*)(bptr);
    bf16x8 b1 = *(const bf16x8*)(bptr + 32);
    acc[ng] = __builtin_amdgcn_mfma_f32_16x16x32_bf16(a0, b0, acc[ng], 0, 0, 0);
    acc[ng] = __builtin_amdgcn_mfma_f32_16x16x32_bf16(a1, b1, acc[ng], 0, 0, 0);
  }
  #pragma unroll
  for (int r = 0; r < 4; ++r) {
    const int nl = w * 16 + ((lane >> 4) << 2) + r;
    const int n = nt * 64 + nl;
    float vals[4];
    #pragma unroll
    for (int ng = 0; ng < 4; ++ng) vals[ng] = (acc[ng][r] + gateb[ng * 16 + arow]) * itemp;
    float mx = fmaxf(fmaxf(vals[0], vals[1]), fmaxf(vals[2], vals[3]));
    #pragma unroll
    for (int s = 1; s < 16; s <<= 1) mx = fmaxf(mx, __shfl_xor(mx, s));
    float ex[4]; float sum = 0.f;
    #pragma unroll
    for (int ng = 0; ng < 4; ++ng) { ex[ng] = __expf(vals[ng] - mx); sum += ex[ng]; }
    #pragma unroll
    for (int s = 1; s < 16; s <<= 1) sum += __shfl_xor(sum, s);
    const float inv = 1.0f / sum;
    const bool valid = (n < NN);
    #pragma unroll
    for (int ng = 0; ng < 4; ++ng) {
      const int g = ng * 16 + arow;
      float iv = valid ? inver[(int64_t)n * GG + g] : 0.f;
      unsigned short u = valid ? f2bf(ex[ng] * inv * iv) : (unsigned short)0;
      egN[nl * 72 + g] = u;
      egT[g * 72 + nl] = u;
    }
  }
  __syncthreads();
  const int row = tid >> 2, c0 = (tid & 3) << 4;
  {
    ushort8_t v0 = *(ushort8_t*)&egN[row * 72 + c0];
    ushort8_t v1 = *(ushort8_t*)&egN[row * 72 + c0 + 8];
    unsigned short* dst = eigN + ((int64_t)bh * NPAD + nt * 64 + row) * 64 + c0;
    *(ushort8_t*)dst = v0; *(ushort8_t*)(dst + 8) = v1;
  }
  {
    ushort8_t v0 = *(ushort8_t*)&egT[row * 72 + c0];
    ushort8_t v1 = *(ushort8_t*)&egT[row * 72 + c0 + 8];
    unsigned short* dst = eigT + ((int64_t)(bh * 64 + row)) * NPAD + nt * 64 + c0;
    *(ushort8_t*)dst = v0; *(ushort8_t*)(dst + 8) = v1;
  }
}

// ---------------- K4a: spec partials (reg -> global f32, 8-way K split) ----------------
// grid (2, CB*8): 256 blocks/launch -> 1 block/CU across the whole GPU (vs 128 before).
__global__ void k_specA(const unsigned short* __restrict__ eigT,
                        const unsigned short* __restrict__ fxT,
                        float* __restrict__ part) {
  const int q = blockIdx.x, bhl = blockIdx.y;
  const int tid = threadIdx.x, w = tid >> 6, lane = tid & 63;
  const int s = q * 4 + w;
  const int ks0 = (98 * s) >> 3, ks1 = (98 * (s + 1)) >> 3;
  const int arow = lane & 15, col16 = lane >> 4;
  const int koff = col16 * 8;
  const unsigned short* eb = eigT + (int64_t)bhl * 64 * NPAD;
  const unsigned short* fb = fxT + (int64_t)bhl * 64 * NPAD;
  f32x4 acc[4][4] = {};
  for (int ks = ks0; ks < ks1; ++ks) {
    const int k0 = ks * 32 + koff;
    bf16x8 av[4], bv[4];
    #pragma unroll
    for (int mg = 0; mg < 4; ++mg) av[mg] = *(const bf16x8*)(eb + (int64_t)(mg * 16 + arow) * NPAD + k0);
    #pragma unroll
    for (int ng = 0; ng < 4; ++ng) bv[ng] = *(const bf16x8*)(fb + (int64_t)(ng * 16 + arow) * NPAD + k0);
    #pragma unroll
    for (int mg = 0; mg < 4; ++mg)
      #pragma unroll
      for (int ng = 0; ng < 4; ++ng)
        acc[mg][ng] = __builtin_amdgcn_mfma_f32_16x16x32_bf16(av[mg], bv[ng], acc[mg][ng], 0, 0, 0);
  }
  float* pb = part + ((int64_t)bhl * 8 + s) * 4096;
  #pragma unroll
  for (int mg = 0; mg < 4; ++mg)
    #pragma unroll
    for (int ng = 0; ng < 4; ++ng)
      #pragma unroll
      for (int r = 0; r < 4; ++r)
        pb[(mg * 16 + col16 * 4 + r) * 64 + ng * 16 + arow] = acc[mg][ng][r];
}

// ---------------- K4b: sum partials, LayerNorm, (LN(spec) @ Pt_h) -> m2t ----------------
__global__ void k_specB(const float* __restrict__ part,
                        const float* __restrict__ gamma, const float* __restrict__ beta,
                        const unsigned short* __restrict__ Pt,
                        unsigned short* __restrict__ m2t) {
  __shared__ unsigned short specb[64 * 64];     // swizzled bf16
  __shared__ float red[8];
  __shared__ unsigned short mstrip[4 * 64 * 72];
  const int bhl = blockIdx.x;
  const int h = bhl & 7, bl = bhl >> 3;
  const int tid = threadIdx.x, w = tid >> 6, lane = tid & 63;
  const int arow = lane & 15, col16 = lane >> 4;
  const int koff = col16 * 8;
  const float* pb = part + (int64_t)bhl * 8 * 4096;

  float vloc[16];
  float lsum = 0.f, lsq = 0.f;
  #pragma unroll
  for (int idx = 0; idx < 16; ++idx) {
    const int e = tid + idx * 256;
    float v = 0.f;
    #pragma unroll
    for (int s = 0; s < 8; ++s) v += pb[s * 4096 + e];
    vloc[idx] = v; lsum += v; lsq += v * v;
  }
  #pragma unroll
  for (int s = 1; s < 64; s <<= 1) { lsum += __shfl_xor(lsum, s); lsq += __shfl_xor(lsq, s); }
  if (lane == 0) { red[w] = lsum; red[4 + w] = lsq; }
  __syncthreads();
  const float tsum = red[0] + red[1] + red[2] + red[3];
  const float tsq = red[4] + red[5] + red[6] + red[7];
  const float mu = tsum * (1.0f / 4096.0f);
  const float var = tsq * (1.0f / 4096.0f) - mu * mu;
  const float rs = rsqrtf(var + 1e-5f);
  #pragma unroll
  for (int idx = 0; idx < 16; ++idx) {
    const int e = tid + idx * 256;
    const int g = e >> 6, c = e & 63;
    float sv = (vloc[idx] - mu) * rs * gamma[e] + beta[e];
    specb[g * 64 + ((((c >> 3) ^ (g & 7))) << 3) + (c & 7)] = f2bf(sv);
  }
  __syncthreads();

  f32x4 a2[4][4] = {};
  const unsigned short* pth = Pt + ((int64_t)h * 256 + w * 64) * 64;
  #pragma unroll
  for (int kk = 0; kk < 2; ++kk) {
    const int i0 = kk * 32 + koff;
    const int i8 = (i0 >> 3);
    bf16x8 av2[4], bv2[4];
    #pragma unroll
    for (int mg = 0; mg < 4; ++mg) {
      const int g = mg * 16 + arow;
      av2[mg] = *(const bf16x8*)(specb + g * 64 + ((i8 ^ (g & 7)) << 3));
    }
    #pragma unroll
    for (int ng = 0; ng < 4; ++ng)
      bv2[ng] = *(const bf16x8*)(pth + (ng * 16 + arow) * 64 + i0);
    #pragma unroll
    for (int mg = 0; mg < 4; ++mg)
      #pragma unroll
      for (int ng = 0; ng < 4; ++ng)
        a2[mg][ng] = __builtin_amdgcn_mfma_f32_16x16x32_bf16(av2[mg], bv2[ng], a2[mg][ng], 0, 0, 0);
  }
  unsigned short* ms = mstrip + w * (64 * 72);
  #pragma unroll
  for (int mg = 0; mg < 4; ++mg)
    #pragma unroll
    for (int ng = 0; ng < 4; ++ng)
      #pragma unroll
      for (int r = 0; r < 4; ++r)
        ms[(ng * 16 + arow) * 72 + mg * 16 + col16 * 4 + r] = f2bf(a2[mg][ng][r]);
  __syncthreads();
  #pragma unroll
  for (int e0 = 0; e0 < 8; ++e0) {
    const int e = lane + e0 * 64;
    const int row = e >> 3, g8 = e & 7;
    ushort8_t v = *(ushort8_t*)&ms[row * 72 + g8 * 8];
    *(ushort8_t*)(m2t + ((int64_t)(bl * 256 + w * 64 + row)) * 512 + h * 64 + g8 * 8) = v;
  }
}

// ---------------- K5: final out GEMM ----------------
__launch_bounds__(256)
__global__ void k_out(const unsigned short* __restrict__ eigN,
                      const unsigned short* __restrict__ m2t,
                      const float* __restrict__ outb,
                      float* __restrict__ out, int b0) {
  const int swz = xcd_swz(blockIdx.x, gridDim.x);
  const int ct = swz & 1;
  const int mt = (swz >> 1) % 25;
  const int b  = swz / 50;
  const int w = threadIdx.x >> 6, lane = threadIdx.x & 63;
  const int wm = w >> 1, wn = w & 1;
  const int arow = lane & 15, koff = (lane >> 4) * 8;
  const int co0 = ct * 128 + wn * 64;
  const int n0 = mt * 128 + wm * 64;
  f32x4 acc[4][4] = {};
  const unsigned short* ebase = eigN + (int64_t)b * NH * NPAD * 64;
  const unsigned short* mbase = m2t + (int64_t)b * 256 * 512;
  for (int ks = 0; ks < 16; ++ks) {
    const int hh = ks >> 1;
    const int g0 = (ks & 1) * 32 + koff;
    bf16x8 av[4], bv[4];
    #pragma unroll
    for (int mg = 0; mg < 4; ++mg) {
      int n = n0 + mg * 16 + arow;
      if (n > NPAD - 1) n = NPAD - 1;
      av[mg] = *(const bf16x8*)(ebase + ((int64_t)hh * NPAD + n) * 64 + g0);
    }
    #pragma unroll
    for (int ng = 0; ng < 4; ++ng)
      bv[ng] = *(const bf16x8*)(mbase + (int64_t)(co0 + ng * 16 + arow) * 512 + ks * 32 + koff);
    #pragma unroll
    for (int mg = 0; mg < 4; ++mg)
      #pragma unroll
      for (int ng = 0; ng < 4; ++ng)
        acc[mg][ng] = __builtin_amdgcn_mfma_f32_16x16x32_bf16(av[mg], bv[ng], acc[mg][ng], 0, 0, 0);
  }
  #pragma unroll
  for (int mg = 0; mg < 4; ++mg) {
    const int nr = n0 + mg * 16 + ((lane >> 4) << 2);
    #pragma unroll
    for (int ng = 0; ng < 4; ++ng) {
      const int co = co0 + ng * 16 + arow;
      const float bv = outb[co];
      #pragma unroll
      for (int r = 0; r < 4; ++r) {
        if (nr + r < NN)
          out[((int64_t)(b0 + b) * NN + nr + r) * 256 + co] = acc[mg][ng][r] + bv;
      }
    }
  }
}

extern "C" void kernel_launch(void* const* d_in, const int* in_sizes, int n_in,
                              void* d_out, int out_size, void* d_ws, size_t ws_size,
                              hipStream_t stream) {
  const float* x     = (const float*)d_in[0];
  const float* fxw   = (const float*)d_in[1];
  const float* fxb   = (const float*)d_in[2];
  const float* xw    = (const float*)d_in[3];
  const float* xb    = (const float*)d_in[4];
  const float* gw    = (const float*)d_in[5];
  const float* gb    = (const float*)d_in[6];
  const float* temp  = (const float*)d_in[7];
  const float* gamma = (const float*)d_in[8];
  const float* beta  = (const float*)d_in[9];
  const float* mlp   = (const float*)d_in[10];
  const float* outw  = (const float*)d_in[11];
  const float* outb  = (const float*)d_in[12];
  const float* inver = (const float*)d_in[13];
  float* out = (float*)d_out;
  char* ws = (char*)d_ws;
  (void)in_sizes; (void)n_in; (void)out_size;

  hipFuncSetAttribute(reinterpret_cast<const void*>(k_conv8),
                      hipFuncAttributeMaxDynamicSharedMemorySize, 131072);

  // CB capped at 16 (R10 lesson: CB=32 overflows per-XCD L2 working set for conv)
  int CB = 1;
  {
    const int cands[5] = {16, 8, 4, 2, 1};
    for (int i = 0; i < 5; ++i) {
      unsigned long long need = 4993024ull + (unsigned long long)cands[i] * 14847488ull;
      if (need <= (unsigned long long)ws_size) { CB = cands[i]; break; }
    }
  }

  unsigned short* Wb   = (unsigned short*)(ws + 0);
  float*          bias = (float*)(ws + 4718592);
  unsigned short* gwb  = (unsigned short*)(ws + 4722688);
  unsigned short* Pt   = (unsigned short*)(ws + 4730880);
  const size_t F0      = 4993024;
  const size_t szXpad  = (size_t)CB * 1740288;
  const size_t szM2t   = (size_t)CB * 262144;
  const size_t szBig   = (size_t)CB * 3211264;
  unsigned short* xpad = (unsigned short*)(ws + F0);
  float*          part = (float*)(ws + F0);   // aliases xpad: CB*8*8*4096*4B = CB*1,048,576
                                              // <= szXpad (CB*1,740,288); xpad dead after conv
  unsigned short* m2t  = (unsigned short*)(ws + F0 + szXpad);
  unsigned short* fxT  = (unsigned short*)(ws + F0 + szXpad + szM2t);
  unsigned short* xmid = (unsigned short*)(ws + F0 + szXpad + szM2t + szBig);
  unsigned short* eigT = (unsigned short*)(ws + F0 + szXpad + szM2t + 2 * szBig);
  unsigned short* eigN = (unsigned short*)(ws + F0 + szXpad + szM2t + 3 * szBig);

  k_wpack<<<dim3(9216), dim3(256), 0, stream>>>(fxw, xw, fxb, xb, gw, Wb, bias, gwb);
  k_pprep<<<dim3(512), dim3(256), 0, stream>>>(mlp, outw, Pt);

  for (int b0 = 0; b0 < BB; b0 += CB) {
    k_pad<<<dim3(WP, HP, CB), dim3(64), 0, stream>>>(x, xpad, b0);
    k_padzero<<<dim3(CB * 10), dim3(256), 0, stream>>>(fxT, xmid, CB);
    k_conv8<<<dim3(52 * CB), dim3(512), 131072, stream>>>(xpad, Wb, bias, fxT, xmid);
    k_eig<<<dim3(49, 8, CB), dim3(256), 0, stream>>>(xmid, gwb, gb, temp, inver, eigT, eigN);
    k_specA<<<dim3(2, CB * 8), dim3(256), 0, stream>>>(eigT, fxT, part);
    k_specB<<<dim3(CB * 8), dim3(256), 0, stream>>>(part, gamma, beta, Pt, m2t);
    k_out<<<dim3(50 * CB), dim3(256), 0, stream>>>(eigN, m2t, outb, out, b0);
  }
}